// Round 19
// baseline (36.870 us; speedup 1.0000x reference)
//
#include <hip/hip_runtime.h>
#include <math.h>

#define NROWS 65536
#define DDIM 512
#define NUM_CLASSES 1000
#define CG 16                      // column groups (32 floats = 128 B each)
#define RC 16                      // row chunks
#define RPB (NROWS / RC)           // 4096 rows per block
#define CSTRIDE 36                 // LDS center-slice stride: 16B-aligned, bank-rotating
#define NRED 250                   // K2 blocks (4 classes each)

// ws layout (floats): [0, 256000) partials[1000][256] class-major
//   [256000] = sqrt-sum accumulator (f32)   [256001] = completion counter (int)
#define PART_OFF 0
#define ACC_OFF (256 * NUM_CLASSES)
#define CNT_OFF (ACC_OFF + 1)
#define WS_NEED ((size_t)(CNT_OFF + 1) * 4)

__device__ inline float sqdiff4(float4 a, float4 b) {
    float dx = a.x - b.x, dy = a.y - b.y, dz = a.z - b.z, dw = a.w - b.w;
    return fmaf(dx, dx, fmaf(dy, dy, fmaf(dz, dz, dw * dw)));
}

// --- K1: column-sliced accumulate, centers slice resident in LDS ---
__global__ __launch_bounds__(1024) void CL_slice(
    const float* __restrict__ x,
    const int* __restrict__ labels,
    const float* __restrict__ centers,
    float* __restrict__ wsF)
{
    __shared__ float cs[NUM_CLASSES * CSTRIDE];   // 144,000 B
    __shared__ float bins[NUM_CLASSES];           //   4,000 B
    const int t  = threadIdx.x;
    const int cg = blockIdx.x & (CG - 1);
    const int rc = blockIdx.x >> 4;
    const int cq = t & 7;                         // col quad within slice
    const int tr = t >> 3;                        // 0..127

    // zero the cross-kernel accumulator/counter (published by launch boundary)
    if (blockIdx.x == 0 && t == 0) {
        wsF[ACC_OFF] = 0.0f;
        reinterpret_cast<int*>(wsF)[CNT_OFF] = 0;
    }

    // stage centers slice [1000][32] -> cs (ds_write_b128, 16B-aligned)
    for (int k = tr; k < NUM_CLASSES; k += 128) {
        const float4 c = *reinterpret_cast<const float4*>(
            centers + (size_t)k * DDIM + cg * 32 + cq * 4);
        *reinterpret_cast<float4*>(cs + k * CSTRIDE + cq * 4) = c;
    }
    if (t < NUM_CLASSES) bins[t] = 0.0f;
    __syncthreads();

    const int rowbase = rc * RPB;
    const float* __restrict__ xcg = x + cg * 32 + cq * 4;

#pragma unroll 4
    for (int i = 0; i < RPB; i += 256) {
        const int rA = rowbase + i + tr;
        const int rB = rA + 128;
        const float4 xa = *reinterpret_cast<const float4*>(xcg + (size_t)rA * DDIM);
        const float4 xb = *reinterpret_cast<const float4*>(xcg + (size_t)rB * DDIM);
        const int la = labels[rA];
        const int lb = labels[rB];
        const float4 ca = *reinterpret_cast<const float4*>(cs + la * CSTRIDE + cq * 4);
        const float4 cb = *reinterpret_cast<const float4*>(cs + lb * CSTRIDE + cq * 4);

        float sa = sqdiff4(xa, ca);
        float sb = sqdiff4(xb, cb);
        // reduce across the 8 lanes of this row (xor 1,2,4 stays in-group)
        sa += __shfl_xor(sa, 1, 64);  sb += __shfl_xor(sb, 1, 64);
        sa += __shfl_xor(sa, 2, 64);  sb += __shfl_xor(sb, 2, 64);
        sa += __shfl_xor(sa, 4, 64);  sb += __shfl_xor(sb, 4, 64);
        if (cq == 0) {
            atomicAdd(&bins[la], sa);     // LDS atomic, block-local
            atomicAdd(&bins[lb], sb);
        }
    }

    __syncthreads();
    // class-major store: partials[class][block] -> K2 reads contiguous runs
    if (t < NUM_CLASSES)
        wsF[PART_OFF + (size_t)t * 256 + blockIdx.x] = bins[t];
}

// --- K2 (fused finalize): 250 blocks x 4 classes. Coalesced reduce + sqrt,
// one atomicAdd of the block's sqrt-sum, last block writes out.
// Cross-block comms are atomics only (no fences): R2 lesson intact; pattern
// validated in R5 (relaxed agent counter + vmcnt drain passed correctness). ---
__global__ __launch_bounds__(256) void CL_reduce_fused(
    float* __restrict__ wsF, float* __restrict__ out)
{
    const int t = threadIdx.x, lane = t & 63, w = t >> 6;
    const int k = blockIdx.x * 4 + w;             // this wave's class
    const float4 v =
        reinterpret_cast<const float4*>(wsF + PART_OFF + (size_t)k * 256)[lane];
    float s = (v.x + v.y) + (v.z + v.w);
#pragma unroll
    for (int off = 32; off > 0; off >>= 1)
        s += __shfl_xor(s, off, 64);

    __shared__ float sq4[4];
    __shared__ int lastflag;
    if (lane == 0) sq4[w] = sqrtf(s);
    __syncthreads();

    if (t == 0) {
        const float blocksum = (sq4[0] + sq4[1]) + (sq4[2] + sq4[3]);
        atomicAdd(&wsF[ACC_OFF], blocksum);
        // my ACC add is at the coherence point before the counter bump
        asm volatile("s_waitcnt vmcnt(0)" ::: "memory");
        int* cnt = reinterpret_cast<int*>(wsF) + CNT_OFF;
        const int prev = __hip_atomic_fetch_add(cnt, 1, __ATOMIC_RELAXED,
                                                __HIP_MEMORY_SCOPE_AGENT);
        lastflag = (prev == NRED - 1) ? 1 : 0;
    }
    __syncthreads();

    if (lastflag && t == 0) {
        const float tot = __hip_atomic_load(&wsF[ACC_OFF], __ATOMIC_RELAXED,
                                            __HIP_MEMORY_SCOPE_AGENT);
        out[0] = tot / (float)NUM_CLASSES;
    }
}

// ---------------- fallback (proven R8, 36.9 µs) if ws too small ----------------
#define NSHARD 8
__global__ __launch_bounds__(256) void CL_zero8(float* __restrict__ ws) {
    const int n = NSHARD * 1024;
    for (int i = threadIdx.x + blockIdx.x * 256; i < n; i += 256 * 8) ws[i] = 0.0f;
}
__global__ __launch_bounds__(256) void CL_accum8(
    const float* __restrict__ x, const int* __restrict__ labels,
    const float* __restrict__ centers, float* __restrict__ ws)
{
    const int wave = threadIdx.x >> 6, lane = threadIdx.x & 63;
    const int row = (blockIdx.x << 2) + wave;
    const int lbl = labels[row];
    const float4* xr = (const float4*)(x + (size_t)row * DDIM);
    const float4* cr = (const float4*)(centers + (size_t)lbl * DDIM);
    float acc = sqdiff4(xr[lane], cr[lane]) + sqdiff4(xr[lane + 64], cr[lane + 64]);
#pragma unroll
    for (int off = 32; off > 0; off >>= 1) acc += __shfl_xor(acc, off, 64);
    if (lane == 0)
        atomicAdd(&ws[((blockIdx.x & (NSHARD - 1)) << 10) + lbl], acc);
}
__global__ __launch_bounds__(256) void CL_final8(
    const float* __restrict__ ws, float* __restrict__ out)
{
    const int t = threadIdx.x, lane = t & 63;
    float s = 0.0f;
    if (t < NUM_CLASSES / 4) {
        float4 v = reinterpret_cast<const float4*>(ws)[t];
#pragma unroll
        for (int sh = 1; sh < NSHARD; ++sh) {
            float4 u = reinterpret_cast<const float4*>(ws + (sh << 10))[t];
            v.x += u.x; v.y += u.y; v.z += u.z; v.w += u.w;
        }
        s = sqrtf(v.x) + sqrtf(v.y) + sqrtf(v.z) + sqrtf(v.w);
    }
#pragma unroll
    for (int off = 32; off > 0; off >>= 1) s += __shfl_xor(s, off, 64);
    __shared__ float partial[4];
    if (lane == 0) partial[t >> 6] = s;
    __syncthreads();
    if (t == 0)
        out[0] = (partial[0] + partial[1] + partial[2] + partial[3]) / (float)NUM_CLASSES;
}

extern "C" void kernel_launch(void* const* d_in, const int* in_sizes, int n_in,
                              void* d_out, int out_size, void* d_ws, size_t ws_size,
                              hipStream_t stream) {
    const float* x       = (const float*)d_in[0];
    const int*   labels  = (const int*)d_in[1];
    const float* centers = (const float*)d_in[2];
    float* out = (float*)d_out;
    float* ws  = (float*)d_ws;

    if (ws_size >= WS_NEED) {
        CL_slice<<<CG * RC, 1024, 0, stream>>>(x, labels, centers, ws);
        CL_reduce_fused<<<NRED, 256, 0, stream>>>(ws, out);
    } else {
        CL_zero8<<<8, 256, 0, stream>>>(ws);
        CL_accum8<<<NROWS / 4, 256, 0, stream>>>(x, labels, centers, ws);
        CL_final8<<<1, 256, 0, stream>>>(ws, out);
    }
}

// Round 20
// 32.650 us; speedup vs baseline: 1.1293x; 1.1293x over previous
//
#include <hip/hip_runtime.h>
#include <math.h>

#define NROWS 65536
#define DDIM 512
#define NUM_CLASSES 1000
#define CG 16                      // column groups (32 floats = 128 B each)
#define RC 16                      // row chunks
#define RPB (NROWS / RC)           // 4096 rows per block
#define CSTRIDE 36                 // LDS center-slice stride: 16B-aligned, bank-rotating

// ws layout: [0, 256000) float partials[1000][256]  (class-major!)
//            [256000, 257000) sqrt vals
#define PART_OFF 0
#define SQRT_OFF (256 * NUM_CLASSES)
#define WS_NEED ((size_t)(SQRT_OFF + NUM_CLASSES) * 4)

__device__ inline float sqdiff4(float4 a, float4 b) {
    float dx = a.x - b.x, dy = a.y - b.y, dz = a.z - b.z, dw = a.w - b.w;
    return fmaf(dx, dx, fmaf(dy, dy, fmaf(dz, dz, dw * dw)));
}

// --- K1: column-sliced accumulate, centers slice resident in LDS ---
__global__ __launch_bounds__(1024) void CL_slice(
    const float* __restrict__ x,
    const int* __restrict__ labels,
    const float* __restrict__ centers,
    float* __restrict__ partials)
{
    __shared__ float cs[NUM_CLASSES * CSTRIDE];   // 144,000 B
    __shared__ float bins[NUM_CLASSES];           //   4,000 B
    const int t  = threadIdx.x;
    const int cg = blockIdx.x & (CG - 1);
    const int rc = blockIdx.x >> 4;
    const int cq = t & 7;                         // col quad within slice
    const int tr = t >> 3;                        // 0..127

    // stage centers slice [1000][32] -> cs (ds_write_b128, 16B-aligned)
    for (int k = tr; k < NUM_CLASSES; k += 128) {
        const float4 c = *reinterpret_cast<const float4*>(
            centers + (size_t)k * DDIM + cg * 32 + cq * 4);
        *reinterpret_cast<float4*>(cs + k * CSTRIDE + cq * 4) = c;
    }
    if (t < NUM_CLASSES) bins[t] = 0.0f;
    __syncthreads();

    const int rowbase = rc * RPB;
    const float* __restrict__ xcg = x + cg * 32 + cq * 4;

#pragma unroll 4
    for (int i = 0; i < RPB; i += 256) {
        const int rA = rowbase + i + tr;
        const int rB = rA + 128;
        const float4 xa = *reinterpret_cast<const float4*>(xcg + (size_t)rA * DDIM);
        const float4 xb = *reinterpret_cast<const float4*>(xcg + (size_t)rB * DDIM);
        const int la = labels[rA];
        const int lb = labels[rB];
        const float4 ca = *reinterpret_cast<const float4*>(cs + la * CSTRIDE + cq * 4);
        const float4 cb = *reinterpret_cast<const float4*>(cs + lb * CSTRIDE + cq * 4);

        float sa = sqdiff4(xa, ca);
        float sb = sqdiff4(xb, cb);
        // reduce across the 8 lanes of this row (xor 1,2,4 stays in-group)
        sa += __shfl_xor(sa, 1, 64);  sb += __shfl_xor(sb, 1, 64);
        sa += __shfl_xor(sa, 2, 64);  sb += __shfl_xor(sb, 2, 64);
        sa += __shfl_xor(sa, 4, 64);  sb += __shfl_xor(sb, 4, 64);
        if (cq == 0) {
            atomicAdd(&bins[la], sa);     // LDS atomic, block-local
            atomicAdd(&bins[lb], sb);
        }
    }

    __syncthreads();
    // class-major store: partials[class][block] -> K2 reads contiguous runs
    if (t < NUM_CLASSES)
        partials[(size_t)t * 256 + blockIdx.x] = bins[t];
}

// --- K2: one wave per class; 256 contiguous partials -> coalesced float4 ---
__global__ __launch_bounds__(256) void CL_reduce(
    const float* __restrict__ partials, float* __restrict__ sqv)
{
    const int t = threadIdx.x, lane = t & 63;
    const int k = blockIdx.x * 4 + (t >> 6);      // this wave's class
    const float4 v =
        reinterpret_cast<const float4*>(partials + (size_t)k * 256)[lane];
    float s = (v.x + v.y) + (v.z + v.w);
#pragma unroll
    for (int off = 32; off > 0; off >>= 1)
        s += __shfl_xor(s, off, 64);
    if (lane == 0) sqv[k] = sqrtf(s);
}

// --- K3: sum the 1000 sqrt values, scale ---
__global__ __launch_bounds__(256) void CL_sum(
    const float* __restrict__ sqv, float* __restrict__ out)
{
    const int t = threadIdx.x, lane = t & 63;
    float s = 0.0f;
    if (t < NUM_CLASSES / 4) {
        const float4 v = reinterpret_cast<const float4*>(sqv)[t];
        s = (v.x + v.y) + (v.z + v.w);
    }
#pragma unroll
    for (int off = 32; off > 0; off >>= 1)
        s += __shfl_xor(s, off, 64);
    __shared__ float partial[4];
    if (lane == 0) partial[t >> 6] = s;
    __syncthreads();
    if (t == 0)
        out[0] = (partial[0] + partial[1] + partial[2] + partial[3])
                 / (float)NUM_CLASSES;
}

// ---------------- fallback (proven R8, 36.9 µs) if ws too small ----------------
#define NSHARD 8
__global__ __launch_bounds__(256) void CL_zero8(float* __restrict__ ws) {
    const int n = NSHARD * 1024;
    for (int i = threadIdx.x + blockIdx.x * 256; i < n; i += 256 * 8) ws[i] = 0.0f;
}
__global__ __launch_bounds__(256) void CL_accum8(
    const float* __restrict__ x, const int* __restrict__ labels,
    const float* __restrict__ centers, float* __restrict__ ws)
{
    const int wave = threadIdx.x >> 6, lane = threadIdx.x & 63;
    const int row = (blockIdx.x << 2) + wave;
    const int lbl = labels[row];
    const float4* xr = (const float4*)(x + (size_t)row * DDIM);
    const float4* cr = (const float4*)(centers + (size_t)lbl * DDIM);
    float acc = sqdiff4(xr[lane], cr[lane]) + sqdiff4(xr[lane + 64], cr[lane + 64]);
#pragma unroll
    for (int off = 32; off > 0; off >>= 1) acc += __shfl_xor(acc, off, 64);
    if (lane == 0)
        atomicAdd(&ws[((blockIdx.x & (NSHARD - 1)) << 10) + lbl], acc);
}
__global__ __launch_bounds__(256) void CL_final8(
    const float* __restrict__ ws, float* __restrict__ out)
{
    const int t = threadIdx.x, lane = t & 63;
    float s = 0.0f;
    if (t < NUM_CLASSES / 4) {
        float4 v = reinterpret_cast<const float4*>(ws)[t];
#pragma unroll
        for (int sh = 1; sh < NSHARD; ++sh) {
            float4 u = reinterpret_cast<const float4*>(ws + (sh << 10))[t];
            v.x += u.x; v.y += u.y; v.z += u.z; v.w += u.w;
        }
        s = sqrtf(v.x) + sqrtf(v.y) + sqrtf(v.z) + sqrtf(v.w);
    }
#pragma unroll
    for (int off = 32; off > 0; off >>= 1) s += __shfl_xor(s, off, 64);
    __shared__ float partial[4];
    if (lane == 0) partial[t >> 6] = s;
    __syncthreads();
    if (t == 0)
        out[0] = (partial[0] + partial[1] + partial[2] + partial[3]) / (float)NUM_CLASSES;
}

extern "C" void kernel_launch(void* const* d_in, const int* in_sizes, int n_in,
                              void* d_out, int out_size, void* d_ws, size_t ws_size,
                              hipStream_t stream) {
    const float* x       = (const float*)d_in[0];
    const int*   labels  = (const int*)d_in[1];
    const float* centers = (const float*)d_in[2];
    float* out = (float*)d_out;
    float* ws  = (float*)d_ws;

    if (ws_size >= WS_NEED) {
        CL_slice<<<CG * RC, 1024, 0, stream>>>(x, labels, centers, ws + PART_OFF);
        CL_reduce<<<NUM_CLASSES / 4, 256, 0, stream>>>(ws + PART_OFF, ws + SQRT_OFF);
        CL_sum<<<1, 256, 0, stream>>>(ws + SQRT_OFF, out);
    } else {
        CL_zero8<<<8, 256, 0, stream>>>(ws);
        CL_accum8<<<NROWS / 4, 256, 0, stream>>>(x, labels, centers, ws);
        CL_final8<<<1, 256, 0, stream>>>(ws, out);
    }
}